// Round 14
// baseline (378.330 us; speedup 1.0000x reference)
//
#include <hip/hip_runtime.h>

#define KDIM 1024
#define NDIM 4096

typedef __attribute__((ext_vector_type(4))) float f32x4;
typedef __attribute__((ext_vector_type(8))) short s16x8;
typedef __attribute__((ext_vector_type(8))) unsigned short u16x8;

__device__ __forceinline__ unsigned short f2bf(float f) {
    union { float f; unsigned u; } v; v.f = f;
    unsigned r = v.u + 0x7FFFu + ((v.u >> 16) & 1u);
    return (unsigned short)(r >> 16);
}

#define GLDS(gsrc, ldst)                                                        \
    __builtin_amdgcn_global_load_lds(                                           \
        (const __attribute__((address_space(1))) unsigned int*)(gsrc),          \
        (__attribute__((address_space(3))) unsigned int*)(ldst), 16, 0, 0)

#define SBAR() __builtin_amdgcn_s_barrier()
#define VMW(n) asm volatile("s_waitcnt vmcnt(" #n ")" ::: "memory")
#define LG0()  do { asm volatile("s_waitcnt lgkmcnt(0)" ::: "memory");          \
                    __builtin_amdgcn_sched_barrier(0); } while (0)

__device__ __forceinline__ void row_coeffs(int o, const float* w,
                                           float& rp0, float& rp1, float& rp2) {
    rp2 = (o < 2048 ? w[6] : 0.f) + (o < 3072 ? w[7] : 0.f) + w[8];
    rp1 = rp2 + (o < 1536 ? w[3] : 0.f) + (o < 2304 ? w[4] : 0.f) + (o < 3072 ? w[5] : 0.f);
    rp0 = rp1 + (o < 1024 ? w[0] : 0.f) + (o < 1536 ? w[1] : 0.f) + (o < 2048 ? w[2] : 0.f);
}

__device__ __forceinline__ float row_bias_coef(int n, const float* w) {
    return (n < 1024 ? w[0] : 0.f) + (n < 1536 ? w[1] : 0.f)
         + (n < 2048 ? w[2] : 0.f) + (n < 1536 ? w[3] : 0.f)
         + (n < 2304 ? w[4] : 0.f) + (n < 3072 ? w[5] : 0.f)
         + (n < 2048 ? w[6] : 0.f) + (n < 3072 ? w[7] : 0.f) + w[8];
}

// ---------------- fused pre-pass: X panels + W_mix panels (v9 layout, coalesced) ----------------
// Panel p = tile*32 + kt: 16KB = 1024 chunks of 16B; chunk c = row*4 + kc_phys,
// kc_phys = (c&3) ^ ((row>>1)&3). X: m_tile in [0,128), 256 rows. W: n_tile in [0,16).
__global__ __launch_bounds__(256) void prep_all(const float* __restrict__ X,
                                                const float* __restrict__ W,
                                                const float* __restrict__ wts,
                                                unsigned short* __restrict__ XB,
                                                unsigned short* __restrict__ WB,
                                                int xchunks, int totchunks) {
    const int g = blockIdx.x * 256 + threadIdx.x;
    if (g >= totchunks) return;
    if (g < xchunks) {
        const int c   = g & 1023;
        const int p   = g >> 10;           // m_tile*32 + kt
        const int kt  = p & 31;
        const int mt  = p >> 5;
        const int row = c >> 2;
        const int kcl = (c & 3) ^ ((row >> 1) & 3);
        const float* src = X + ((size_t)(mt * 256 + row) * KDIM + kt * 32 + kcl * 8);
        f32x4 a = *(const f32x4*)src, b = *(const f32x4*)(src + 4);
        u16x8 o;
        o[0] = f2bf(a[0]); o[1] = f2bf(a[1]); o[2] = f2bf(a[2]); o[3] = f2bf(a[3]);
        o[4] = f2bf(b[0]); o[5] = f2bf(b[1]); o[6] = f2bf(b[2]); o[7] = f2bf(b[3]);
        *(u16x8*)(XB + (size_t)g * 8) = o;
    } else {
        const int gw  = g - xchunks;
        const int c   = gw & 1023;
        const int p   = gw >> 10;          // n_tile*32 + kt
        const int kt  = p & 31;
        const int nt  = p >> 5;
        const int row = c >> 2;
        const int kcl = (c & 3) ^ ((row >> 1) & 3);
        float w[9];
#pragma unroll
        for (int k = 0; k < 9; ++k) w[k] = wts[k];
        float rp0, rp1, rp2;
        row_coeffs(nt * 256 + row, w, rp0, rp1, rp2);
        const int i0 = kt * 32 + kcl * 8;
        const float cf = i0 < 512 ? rp0 : (i0 < 768 ? rp1 : rp2);
        const float* src = W + ((size_t)(nt * 256 + row) * KDIM + i0);
        f32x4 a = *(const f32x4*)src, b = *(const f32x4*)(src + 4);
        u16x8 o;
        o[0] = f2bf(a[0] * cf); o[1] = f2bf(a[1] * cf); o[2] = f2bf(a[2] * cf); o[3] = f2bf(a[3] * cf);
        o[4] = f2bf(b[0] * cf); o[5] = f2bf(b[1] * cf); o[6] = f2bf(b[2] * cf); o[7] = f2bf(b[3] * cf);
        *(u16x8*)(WB + (size_t)gw * 8) = o;
    }
}

// ---------------- main GEMM v14: 256x256 tile, 1024 threads (16 waves of 64x64) ----------------
// Staged-bytes experiment: total staging = MK*(N/BN) + NK*(M/BM).
//   v13 (128x256): 3.1 GB @ 16 waves/CU -> 315us.   v14 (256x256): 2.0 GB @ 16 waves/CU.
// If staging-rate-bound (~16 B/cyc per 16-wave CU), -35% bytes -> ~15-20% faster.
// Regs: acc 64 AGPR + frags 32 + addr ~20 <= 128 unified (launch_bounds(1024,4)).
// LDS ring-3 96KB (1 block/CU). 2 GLDS/thread/K-tile (A:1, B:1 - each 1KB contiguous
// from v9 panels, linear dest). v13's 2-sub-phase fine interleave + counted VMW(2).
__global__ __launch_bounds__(1024, 4) void mlv2_gemm_v14(
    const unsigned short* __restrict__ XB,   // panels [m_tile*32+kt][1024 chunks]
    const unsigned short* __restrict__ WB,   // panels [n_tile*32+kt][1024 chunks]
    const float* __restrict__ wts,
    const float* __restrict__ bias,
    float* __restrict__ Y)
{
    __shared__ unsigned short LDS[3 * 16384];   // 96 KiB: 3 bufs x (A 16KB + B 16KB)

    const int tid = (int)threadIdx.x;
    const int l   = tid & 63;
    const int w   = tid >> 6;      // wave 0..15
    const int wm  = w >> 2;        // 0..3  (M quarter: 64 rows)
    const int wn  = w & 3;         // 0..3  (N quarter: 64 cols)

    const int bid = (int)blockIdx.x;
    const int xcd = bid & 7;
    const int i   = bid >> 3;                // 0..255
    const int n_tile = xcd * 2 + (i & 1);    // XCD pinned to 2 n-tiles (B 1MB L2-resident)
    const int m_tile = i >> 1;               // 0..127; pair shares m_tile
    const int m0 = m_tile * 256;
    const int n0 = n_tile * 256;

    // frag-read offsets (v9-validated pattern; swizzle collapses to lane constant)
    const int rl = l & 15;
    const unsigned swz = (unsigned)((l >> 4) ^ ((rl >> 1) & 3));
    unsigned offA[4], offB[4];
#pragma unroll
    for (int m = 0; m < 4; ++m)
        offA[m] = ((unsigned)(wm * 64 + m * 16 + rl) * 4u + swz) * 8u;
#pragma unroll
    for (int n = 0; n < 4; ++n)
        offB[n] = 8192u + ((unsigned)(wn * 64 + n * 16 + rl) * 4u + swz) * 8u;

    // staging: wave w covers chunks [w*64, w*64+64) of each panel (1KB contiguous),
    // 1 GLDS for A + 1 for B per K-tile per thread; linear LDS dest.
    const unsigned cS = (unsigned)(w * 64 + l) * 8u;     // src ushort offset in panel
    const unsigned dA = (unsigned)(w * 512);             // LDS ushort offset within buf
    const unsigned dB = 8192u + dA;

    f32x4 acc[4][4];
#pragma unroll
    for (int m = 0; m < 4; ++m)
#pragma unroll
        for (int n = 0; n < 4; ++n) acc[m][n] = (f32x4){0.f, 0.f, 0.f, 0.f};

    s16x8 bfr[4], af2[2];

    // phase a: stage A(kt2)->ob_st | read B[0..3]+A[0,1] from ob_rd | bar | lgkm0 | 8 MFMA | bar
    auto phaseA = [&](unsigned ob_rd, unsigned ob_st, int kt2, bool st) {
        if (st) {
            const unsigned short* pa = XB + ((size_t)(m_tile * 32 + kt2) << 13);
            GLDS(pa + cS, &LDS[ob_st + dA]);
        }
        const unsigned short* base = &LDS[ob_rd];
#pragma unroll
        for (int n = 0; n < 4; ++n) bfr[n] = *(const s16x8*)(base + offB[n]);
        af2[0] = *(const s16x8*)(base + offA[0]);
        af2[1] = *(const s16x8*)(base + offA[1]);
        SBAR();
        LG0();
        __builtin_amdgcn_s_setprio(1);
#pragma unroll
        for (int m = 0; m < 2; ++m)
#pragma unroll
            for (int n = 0; n < 4; ++n)
                acc[m][n] = __builtin_amdgcn_mfma_f32_16x16x32_bf16(
                    af2[m], bfr[n], acc[m][n], 0, 0, 0);
        __builtin_amdgcn_s_setprio(0);
        SBAR();
    };
    // phase b: stage B(kt2) | read A[2,3] | bar | lgkm0 | 8 MFMA | (caller: VMW+SBAR)
    auto phaseB = [&](unsigned ob_rd, unsigned ob_st, int kt2, bool st) {
        if (st) {
            const unsigned short* pb = WB + ((size_t)(n_tile * 32 + kt2) << 13);
            GLDS(pb + cS, &LDS[ob_st + dB]);
        }
        const unsigned short* base = &LDS[ob_rd];
        af2[0] = *(const s16x8*)(base + offA[2]);
        af2[1] = *(const s16x8*)(base + offA[3]);
        SBAR();
        LG0();
        __builtin_amdgcn_s_setprio(1);
#pragma unroll
        for (int m = 0; m < 2; ++m)
#pragma unroll
            for (int n = 0; n < 4; ++n)
                acc[m + 2][n] = __builtin_amdgcn_mfma_f32_16x16x32_bf16(
                    af2[m], bfr[n], acc[m + 2][n], 0, 0, 0);
        __builtin_amdgcn_s_setprio(0);
    };

    // prologue: stage kt0, kt1 (4 loads/thread); VMW(2): kt0 landed, kt1 in flight
    unsigned o0 = 0, o1 = 16384, o2 = 32768;
    {
        const unsigned short* pa0 = XB + ((size_t)(m_tile * 32 + 0) << 13);
        const unsigned short* pb0 = WB + ((size_t)(n_tile * 32 + 0) << 13);
        GLDS(pa0 + cS, &LDS[o0 + dA]); GLDS(pb0 + cS, &LDS[o0 + dB]);
        const unsigned short* pa1 = XB + ((size_t)(m_tile * 32 + 1) << 13);
        const unsigned short* pb1 = WB + ((size_t)(n_tile * 32 + 1) << 13);
        GLDS(pa1 + cS, &LDS[o1 + dA]); GLDS(pb1 + cS, &LDS[o1 + dB]);
    }
    VMW(2);
    SBAR();

    // steady iter kt: reads o0 (buf kt), stages kt+2 into o2 (1 GLDS per phase).
    // End-of-iter VMW(2): own kt+2 loads (A,B) in flight; kt+1 certified landed.
    // Buf safety: o2's previous reads (iter kt-1) retired via LG0 before iter
    // kt-1's final SBAR; this iter's GLDS writes to o2 issue after that barrier.
    for (int kt = 0; kt < 30; ++kt) {
        phaseA(o0, o2, kt + 2, true);
        phaseB(o0, o2, kt + 2, true);
        VMW(2); SBAR();
        const unsigned t_ = o0; o0 = o1; o1 = o2; o2 = t_;
    }
    // kt=30: no staging; drain kt31's loads
    phaseA(o0, 0, 0, false);
    phaseB(o0, 0, 0, false);
    VMW(0); SBAR();
    const unsigned tl = o0; o0 = o1; o1 = o2; o2 = tl;
    // kt=31
    phaseA(o0, 0, 0, false);
    phaseB(o0, 0, 0, false);

    // ---- epilogue: + bias[n] * rowcoef(n)
    float w9[9];
#pragma unroll
    for (int k = 0; k < 9; ++k) w9[k] = wts[k];
    const int gmb = m0 + wm * 64 + (l >> 4) * 4;
    const int gnb = n0 + wn * 64 + rl;
#pragma unroll
    for (int n = 0; n < 4; ++n) {
        const int gn = gnb + n * 16;
        const float bc = bias[gn] * row_bias_coef(gn, w9);
#pragma unroll
        for (int m = 0; m < 4; ++m) {
            float* yp = Y + (size_t)(gmb + m * 16) * NDIM + gn;
            yp[0 * NDIM] = acc[m][n][0] + bc;
            yp[1 * NDIM] = acc[m][n][1] + bc;
            yp[2 * NDIM] = acc[m][n][2] + bc;
            yp[3 * NDIM] = acc[m][n][3] + bc;
        }
    }
}

// ---------------- fallback (round-1 fused kernel, validated) ----------------
__global__ __launch_bounds__(256, 2) void mlv2_gemm_v1(
    const float* __restrict__ X, const float* __restrict__ wts,
    const float* __restrict__ W, const float* __restrict__ bias,
    float* __restrict__ Y)
{
    __shared__ unsigned short Alds[2][4][128][8];
    __shared__ unsigned short Blds[2][4][128][8];
    const int tid = (int)threadIdx.x;
    const int bid = (int)blockIdx.x;
    const int wg  = (bid & 7) * 1024 + (bid >> 3);
    const int n_tile = wg & 31;
    const int m_tile = wg >> 5;
    float w[9];
#pragma unroll
    for (int k = 0; k < 9; ++k) w[k] = wts[k];
    const int srow = tid >> 1;
    const int scol = (tid & 1) << 4;
    const int kc0  = (tid & 1) << 1;
    const float* xp = X + (size_t)(m_tile * 128 + srow) * KDIM + scol;
    const float* wp = W + (size_t)(n_tile * 128 + srow) * KDIM + scol;
    const int orow = n_tile * 128 + srow;
    float rp0, rp1, rp2;
    row_coeffs(orow, w, rp0, rp1, rp2);
    const int lane = tid & 63, wv = tid >> 6;
    const int frow = lane & 15, kcl = lane >> 4;
    const int arow0 = (wv >> 1) * 64 + frow;
    const int brow0 = (wv & 1) * 64 + frow;
    auto coef = [&](int t) -> float { return t < 16 ? rp0 : (t < 24 ? rp1 : rp2); };
    auto stage_load = [&](int t, f32x4 a[4], f32x4 b[4]) {
        const f32x4* xq = (const f32x4*)(xp + t * 32);
        const f32x4* wq = (const f32x4*)(wp + t * 32);
#pragma unroll
        for (int j = 0; j < 4; ++j) { a[j] = xq[j]; b[j] = wq[j]; }
    };
    auto stage_write = [&](int buf, const f32x4 a[4], const f32x4 b[4], float cf) {
        u16x8 va[2], vb[2];
#pragma unroll
        for (int j = 0; j < 4; ++j)
#pragma unroll
            for (int e = 0; e < 4; ++e) {
                const int idx = j * 4 + e;
                va[idx >> 3][idx & 7] = f2bf(a[j][e]);
                vb[idx >> 3][idx & 7] = f2bf(b[j][e] * cf);
            }
        *(u16x8*)&Alds[buf][kc0    ][srow][0] = va[0];
        *(u16x8*)&Alds[buf][kc0 + 1][srow][0] = va[1];
        *(u16x8*)&Blds[buf][kc0    ][srow][0] = vb[0];
        *(u16x8*)&Blds[buf][kc0 + 1][srow][0] = vb[1];
    };
    f32x4 acc[4][4];
#pragma unroll
    for (int i = 0; i < 4; ++i)
#pragma unroll
        for (int j = 0; j < 4; ++j) acc[i][j] = (f32x4){0.f, 0.f, 0.f, 0.f};
    {
        f32x4 a[4], b[4];
        stage_load(0, a, b);
        stage_write(0, a, b, coef(0));
    }
    __syncthreads();
    const int NT = KDIM / 32;
    int cur = 0;
    for (int t = 0; t < NT; ++t) {
        f32x4 a[4], b[4];
        if (t + 1 < NT) stage_load(t + 1, a, b);
        s16x8 af[4], bf_[4];
#pragma unroll
        for (int i = 0; i < 4; ++i) {
            af[i]  = *(const s16x8*)&Alds[cur][kcl][arow0 + i * 16][0];
            bf_[i] = *(const s16x8*)&Blds[cur][kcl][brow0 + i * 16][0];
        }
#pragma unroll
        for (int i = 0; i < 4; ++i)
#pragma unroll
            for (int j = 0; j < 4; ++j)
                acc[i][j] = __builtin_amdgcn_mfma_f32_16x16x32_bf16(
                    af[i], bf_[j], acc[i][j], 0, 0, 0);
        if (t + 1 < NT) stage_write(cur ^ 1, a, b, coef(t + 1));
        __syncthreads();
        cur ^= 1;
    }
    const int gm0 = m_tile * 128 + (wv >> 1) * 64 + kcl * 4;
    const int gn0 = n_tile * 128 + (wv & 1) * 64 + frow;
#pragma unroll
    for (int j = 0; j < 4; ++j) {
        const int n = gn0 + j * 16;
        const float bc = bias[n] * row_bias_coef(n, w);
#pragma unroll
        for (int i = 0; i < 4; ++i) {
            float* yp = Y + (size_t)(gm0 + i * 16) * NDIM + n;
            yp[0 * NDIM] = acc[i][j][0] + bc;
            yp[1 * NDIM] = acc[i][j][1] + bc;
            yp[2 * NDIM] = acc[i][j][2] + bc;
            yp[3 * NDIM] = acc[i][j][3] + bc;
        }
    }
}

extern "C" void kernel_launch(void* const* d_in, const int* in_sizes, int n_in,
                              void* d_out, int out_size, void* d_ws, size_t ws_size,
                              hipStream_t stream) {
    const float* X    = (const float*)d_in[0];
    const float* wts  = (const float*)d_in[1];
    const float* W    = (const float*)d_in[2];
    const float* bias = (const float*)d_in[3];
    float* Y = (float*)d_out;

    const int M = in_sizes[0] / KDIM;            // 32768

    const size_t xb_elems = (size_t)M * KDIM;
    const size_t wb_elems = (size_t)NDIM * KDIM;
    const size_t ws_needed = (xb_elems + wb_elems) * sizeof(unsigned short);

    if (ws_size >= ws_needed && (M % 256) == 0) {
        unsigned short* XB = (unsigned short*)d_ws;
        unsigned short* WB = XB + xb_elems;
        const int xchunks   = (int)(xb_elems / 8);           // 4,194,304
        const int totchunks = xchunks + (int)(wb_elems / 8); // + 524,288
        prep_all<<<(totchunks + 255) / 256, 256, 0, stream>>>(X, W, wts, XB, WB,
                                                              xchunks, totchunks);
        const int grid = (M / 256) * (NDIM / 256);   // 2048
        mlv2_gemm_v14<<<grid, 1024, 0, stream>>>(XB, WB, wts, bias, Y);
    } else {
        const int grid = (M / 128) * (NDIM / 128);
        mlv2_gemm_v1<<<grid, 256, 0, stream>>>(X, wts, W, bias, Y);
    }
}

// Round 15
// 366.987 us; speedup vs baseline: 1.0309x; 1.0309x over previous
//
#include <hip/hip_runtime.h>

#define KDIM 1024
#define NDIM 4096

typedef __attribute__((ext_vector_type(4))) float f32x4;
typedef __attribute__((ext_vector_type(8))) short s16x8;
typedef __attribute__((ext_vector_type(8))) unsigned short u16x8;

__device__ __forceinline__ unsigned short f2bf(float f) {
    union { float f; unsigned u; } v; v.f = f;
    unsigned r = v.u + 0x7FFFu + ((v.u >> 16) & 1u);
    return (unsigned short)(r >> 16);
}

#define GLDS(gsrc, ldst)                                                        \
    __builtin_amdgcn_global_load_lds(                                           \
        (const __attribute__((address_space(1))) unsigned int*)(gsrc),          \
        (__attribute__((address_space(3))) unsigned int*)(ldst), 16, 0, 0)

#define SBAR() __builtin_amdgcn_s_barrier()
#define VMW(n) asm volatile("s_waitcnt vmcnt(" #n ")" ::: "memory")
#define LG0()  do { asm volatile("s_waitcnt lgkmcnt(0)" ::: "memory");          \
                    __builtin_amdgcn_sched_barrier(0); } while (0)

__device__ __forceinline__ void row_coeffs(int o, const float* w,
                                           float& rp0, float& rp1, float& rp2) {
    rp2 = (o < 2048 ? w[6] : 0.f) + (o < 3072 ? w[7] : 0.f) + w[8];
    rp1 = rp2 + (o < 1536 ? w[3] : 0.f) + (o < 2304 ? w[4] : 0.f) + (o < 3072 ? w[5] : 0.f);
    rp0 = rp1 + (o < 1024 ? w[0] : 0.f) + (o < 1536 ? w[1] : 0.f) + (o < 2048 ? w[2] : 0.f);
}

__device__ __forceinline__ float row_bias_coef(int n, const float* w) {
    return (n < 1024 ? w[0] : 0.f) + (n < 1536 ? w[1] : 0.f)
         + (n < 2048 ? w[2] : 0.f) + (n < 1536 ? w[3] : 0.f)
         + (n < 2304 ? w[4] : 0.f) + (n < 3072 ? w[5] : 0.f)
         + (n < 2048 ? w[6] : 0.f) + (n < 3072 ? w[7] : 0.f) + w[8];
}

// ---------------- fused pre-pass (one launch): X panels + W_mix panels ----------------
// XB: panel p = m_tile*32+kt (m_tile in [0,256)), 512 chunks of 16B (8KB):
//     row = c>>2 (128 rows), kc_phys = (c&3) ^ ((row>>1)&3).   [round-10/13 validated]
// WB: panel p = n_tile*32+kt (n_tile in [0,16)), 1024 chunks (16KB), 256 rows.
__global__ __launch_bounds__(256) void prep_all(const float* __restrict__ X,
                                                const float* __restrict__ W,
                                                const float* __restrict__ wts,
                                                unsigned short* __restrict__ XB,
                                                unsigned short* __restrict__ WB,
                                                int xchunks, int totchunks) {
    const int g = blockIdx.x * 256 + threadIdx.x;
    if (g >= totchunks) return;
    if (g < xchunks) {
        const int c   = g & 511;
        const int p   = g >> 9;            // m_tile*32 + kt
        const int kt  = p & 31;
        const int mt  = p >> 5;
        const int row = c >> 2;
        const int kcl = (c & 3) ^ ((row >> 1) & 3);
        const float* src = X + ((size_t)(mt * 128 + row) * KDIM + kt * 32 + kcl * 8);
        f32x4 a = *(const f32x4*)src, b = *(const f32x4*)(src + 4);
        u16x8 o;
        o[0] = f2bf(a[0]); o[1] = f2bf(a[1]); o[2] = f2bf(a[2]); o[3] = f2bf(a[3]);
        o[4] = f2bf(b[0]); o[5] = f2bf(b[1]); o[6] = f2bf(b[2]); o[7] = f2bf(b[3]);
        *(u16x8*)(XB + (size_t)g * 8) = o;
    } else {
        const int gw  = g - xchunks;
        const int c   = gw & 1023;
        const int p   = gw >> 10;          // n_tile*32 + kt
        const int kt  = p & 31;
        const int nt  = p >> 5;
        const int row = c >> 2;
        const int kcl = (c & 3) ^ ((row >> 1) & 3);
        float w[9];
#pragma unroll
        for (int k = 0; k < 9; ++k) w[k] = wts[k];
        float rp0, rp1, rp2;
        row_coeffs(nt * 256 + row, w, rp0, rp1, rp2);
        const int i0 = kt * 32 + kcl * 8;
        const float cf = i0 < 512 ? rp0 : (i0 < 768 ? rp1 : rp2);
        const float* src = W + ((size_t)(nt * 256 + row) * KDIM + i0);
        f32x4 a = *(const f32x4*)src, b = *(const f32x4*)(src + 4);
        u16x8 o;
        o[0] = f2bf(a[0] * cf); o[1] = f2bf(a[1] * cf); o[2] = f2bf(a[2] * cf); o[3] = f2bf(a[3] * cf);
        o[4] = f2bf(b[0] * cf); o[5] = f2bf(b[1] * cf); o[6] = f2bf(b[2] * cf); o[7] = f2bf(b[3] * cf);
        *(u16x8*)(WB + (size_t)gw * 8) = o;
    }
}

// ---------------- main GEMM v13 (MEASURED OPTIMUM, round 13: GEMM ~315us, 873 TF) ----------------
// 128x256 tile, 8 waves of 64x64, launch_bounds(512,4) -> 2 blocks/CU (the decisive
// variable: two async block contexts fill each other's sync bubbles). Ring-3 LDS
// 72KB, 3 GLDS/wave/K-tile (contiguous 1KB panels, linear dest), fine 2-sub-phase
// interleave per K-tile, counted VMW(3) (never 0 mid-loop). 60 VGPR + 64 AGPR.
__global__ __launch_bounds__(512, 4) void mlv2_gemm_v13(
    const unsigned short* __restrict__ XB,   // panels [m_tile*32+kt][512 chunks]
    const unsigned short* __restrict__ WB,   // panels [n_tile*32+kt][1024 chunks]
    const float* __restrict__ wts,
    const float* __restrict__ bias,
    float* __restrict__ Y)
{
    __shared__ unsigned short LDS[3 * 12288];   // 72 KiB: 3 bufs x (A 8KB + B 16KB)

    const int tid = (int)threadIdx.x;
    const int l   = tid & 63;
    const int w   = tid >> 6;      // wave 0..7
    const int wm  = w >> 2;        // 0..1  (M half)
    const int wn  = w & 3;         // 0..3  (N quarter)

    const int bid = (int)blockIdx.x;
    const int xcd = bid & 7;
    const int i   = bid >> 3;                // 0..511
    const int n_tile = xcd * 2 + (i & 1);    // XCD pinned to 2 n-tiles (B L2-resident)
    const int m_tile = i >> 1;               // 0..255; pair shares m_tile
    const int m0 = m_tile * 128;
    const int n0 = n_tile * 256;

    // frag-read offsets (validated; 0 bank conflicts)
    const int rl = l & 15;
    const unsigned swz = (unsigned)((l >> 4) ^ ((rl >> 1) & 3));
    unsigned offA[4], offB[4];
#pragma unroll
    for (int m = 0; m < 4; ++m)
        offA[m] = ((unsigned)(wm * 64 + m * 16 + rl) * 4u + swz) * 8u;
#pragma unroll
    for (int n = 0; n < 4; ++n)
        offB[n] = 4096u + ((unsigned)(wn * 64 + n * 16 + rl) * 4u + swz) * 8u;

    // staging: 3 GLDS/wave/K-tile, contiguous 1KB each, linear dest
    const unsigned cA  = (unsigned)(w * 64 + l) * 8u;     // in A panel (512 chunks)
    const unsigned cB0 = (unsigned)(w * 128 + l) * 8u;    // in B panel (1024 chunks)
    const unsigned cB1 = cB0 + 512u;
    const unsigned dA  = (unsigned)(w * 512);
    const unsigned dB0 = 4096u + (unsigned)(w * 1024);
    const unsigned dB1 = dB0 + 512u;

    f32x4 acc[4][4];
#pragma unroll
    for (int m = 0; m < 4; ++m)
#pragma unroll
        for (int n = 0; n < 4; ++n) acc[m][n] = (f32x4){0.f, 0.f, 0.f, 0.f};

    s16x8 bfr[4], af2[2];

    // phase a: stage A(kt2)+B0(kt2) -> ob_st | read B all + A m0,1 from ob_rd | 8 MFMA
    auto phaseA = [&](unsigned ob_rd, unsigned ob_st, int kt2, bool st) {
        if (st) {
            const unsigned short* pa = XB + ((size_t)(m_tile * 32 + kt2) << 12);
            const unsigned short* pb = WB + ((size_t)(n_tile * 32 + kt2) << 13);
            GLDS(pa + cA,  &LDS[ob_st + dA]);
            GLDS(pb + cB0, &LDS[ob_st + dB0]);
        }
        const unsigned short* base = &LDS[ob_rd];
#pragma unroll
        for (int n = 0; n < 4; ++n) bfr[n] = *(const s16x8*)(base + offB[n]);
        af2[0] = *(const s16x8*)(base + offA[0]);
        af2[1] = *(const s16x8*)(base + offA[1]);
        SBAR();
        LG0();
        __builtin_amdgcn_s_setprio(1);
#pragma unroll
        for (int m = 0; m < 2; ++m)
#pragma unroll
            for (int n = 0; n < 4; ++n)
                acc[m][n] = __builtin_amdgcn_mfma_f32_16x16x32_bf16(
                    af2[m], bfr[n], acc[m][n], 0, 0, 0);
        __builtin_amdgcn_s_setprio(0);
        SBAR();
    };
    // phase b: stage B1(kt2) | read A m2,3 | 8 MFMA | (caller does VMW+SBAR)
    auto phaseB = [&](unsigned ob_rd, unsigned ob_st, int kt2, bool st) {
        if (st) {
            const unsigned short* pb = WB + ((size_t)(n_tile * 32 + kt2) << 13);
            GLDS(pb + cB1, &LDS[ob_st + dB1]);
        }
        const unsigned short* base = &LDS[ob_rd];
        af2[0] = *(const s16x8*)(base + offA[2]);
        af2[1] = *(const s16x8*)(base + offA[3]);
        SBAR();
        LG0();
        __builtin_amdgcn_s_setprio(1);
#pragma unroll
        for (int m = 0; m < 2; ++m)
#pragma unroll
            for (int n = 0; n < 4; ++n)
                acc[m + 2][n] = __builtin_amdgcn_mfma_f32_16x16x32_bf16(
                    af2[m], bfr[n], acc[m + 2][n], 0, 0, 0);
        __builtin_amdgcn_s_setprio(0);
    };

    // prologue: stage kt0, kt1 (6 loads); VMW(3): kt0 landed, kt1's 3 in flight
    unsigned o0 = 0, o1 = 12288, o2 = 24576;
    {
        const unsigned short* pa0 = XB + ((size_t)(m_tile * 32 + 0) << 12);
        const unsigned short* pb0 = WB + ((size_t)(n_tile * 32 + 0) << 13);
        GLDS(pa0 + cA, &LDS[o0 + dA]); GLDS(pb0 + cB0, &LDS[o0 + dB0]); GLDS(pb0 + cB1, &LDS[o0 + dB1]);
        const unsigned short* pa1 = XB + ((size_t)(m_tile * 32 + 1) << 12);
        const unsigned short* pb1 = WB + ((size_t)(n_tile * 32 + 1) << 13);
        GLDS(pa1 + cA, &LDS[o1 + dA]); GLDS(pb1 + cB0, &LDS[o1 + dB0]); GLDS(pb1 + cB1, &LDS[o1 + dB1]);
    }
    VMW(3);
    SBAR();

    // steady: iter kt reads o0 (=buf kt), stages kt+2 into o2.
    // Buf safety: o2's previous reads retired via iter kt-1's LG0, before iter
    // kt-1's end barrier. VMW(3) at end: kt+1 certified landed.
    for (int kt = 0; kt < 30; ++kt) {
        phaseA(o0, o2, kt + 2, true);
        phaseB(o0, o2, kt + 2, true);
        VMW(3); SBAR();
        const unsigned t_ = o0; o0 = o1; o1 = o2; o2 = t_;
    }
    // kt=30: no staging; drain kt31's 3 loads
    phaseA(o0, 0, 0, false);
    phaseB(o0, 0, 0, false);
    VMW(0); SBAR();
    const unsigned tl = o0; o0 = o1; o1 = o2; o2 = tl;
    // kt=31
    phaseA(o0, 0, 0, false);
    phaseB(o0, 0, 0, false);

    // ---- epilogue: + bias[n] * rowcoef(n)
    float w9[9];
#pragma unroll
    for (int k = 0; k < 9; ++k) w9[k] = wts[k];
    const int gmb = m0 + wm * 64 + (l >> 4) * 4;
    const int gnb = n0 + wn * 64 + rl;
#pragma unroll
    for (int n = 0; n < 4; ++n) {
        const int gn = gnb + n * 16;
        const float bc = bias[gn] * row_bias_coef(gn, w9);
#pragma unroll
        for (int m = 0; m < 4; ++m) {
            float* yp = Y + (size_t)(gmb + m * 16) * NDIM + gn;
            yp[0 * NDIM] = acc[m][n][0] + bc;
            yp[1 * NDIM] = acc[m][n][1] + bc;
            yp[2 * NDIM] = acc[m][n][2] + bc;
            yp[3 * NDIM] = acc[m][n][3] + bc;
        }
    }
}

// ---------------- fallback (round-1 fused kernel, validated) ----------------
__global__ __launch_bounds__(256, 2) void mlv2_gemm_v1(
    const float* __restrict__ X, const float* __restrict__ wts,
    const float* __restrict__ W, const float* __restrict__ bias,
    float* __restrict__ Y)
{
    __shared__ unsigned short Alds[2][4][128][8];
    __shared__ unsigned short Blds[2][4][128][8];
    const int tid = (int)threadIdx.x;
    const int bid = (int)blockIdx.x;
    const int wg  = (bid & 7) * 1024 + (bid >> 3);
    const int n_tile = wg & 31;
    const int m_tile = wg >> 5;
    float w[9];
#pragma unroll
    for (int k = 0; k < 9; ++k) w[k] = wts[k];
    const int srow = tid >> 1;
    const int scol = (tid & 1) << 4;
    const int kc0  = (tid & 1) << 1;
    const float* xp = X + (size_t)(m_tile * 128 + srow) * KDIM + scol;
    const float* wp = W + (size_t)(n_tile * 128 + srow) * KDIM + scol;
    const int orow = n_tile * 128 + srow;
    float rp0, rp1, rp2;
    row_coeffs(orow, w, rp0, rp1, rp2);
    const int lane = tid & 63, wv = tid >> 6;
    const int frow = lane & 15, kcl = lane >> 4;
    const int arow0 = (wv >> 1) * 64 + frow;
    const int brow0 = (wv & 1) * 64 + frow;
    auto coef = [&](int t) -> float { return t < 16 ? rp0 : (t < 24 ? rp1 : rp2); };
    auto stage_load = [&](int t, f32x4 a[4], f32x4 b[4]) {
        const f32x4* xq = (const f32x4*)(xp + t * 32);
        const f32x4* wq = (const f32x4*)(wp + t * 32);
#pragma unroll
        for (int j = 0; j < 4; ++j) { a[j] = xq[j]; b[j] = wq[j]; }
    };
    auto stage_write = [&](int buf, const f32x4 a[4], const f32x4 b[4], float cf) {
        u16x8 va[2], vb[2];
#pragma unroll
        for (int j = 0; j < 4; ++j)
#pragma unroll
            for (int e = 0; e < 4; ++e) {
                const int idx = j * 4 + e;
                va[idx >> 3][idx & 7] = f2bf(a[j][e]);
                vb[idx >> 3][idx & 7] = f2bf(b[j][e] * cf);
            }
        *(u16x8*)&Alds[buf][kc0    ][srow][0] = va[0];
        *(u16x8*)&Alds[buf][kc0 + 1][srow][0] = va[1];
        *(u16x8*)&Blds[buf][kc0    ][srow][0] = vb[0];
        *(u16x8*)&Blds[buf][kc0 + 1][srow][0] = vb[1];
    };
    f32x4 acc[4][4];
#pragma unroll
    for (int i = 0; i < 4; ++i)
#pragma unroll
        for (int j = 0; j < 4; ++j) acc[i][j] = (f32x4){0.f, 0.f, 0.f, 0.f};
    {
        f32x4 a[4], b[4];
        stage_load(0, a, b);
        stage_write(0, a, b, coef(0));
    }
    __syncthreads();
    const int NT = KDIM / 32;
    int cur = 0;
    for (int t = 0; t < NT; ++t) {
        f32x4 a[4], b[4];
        if (t + 1 < NT) stage_load(t + 1, a, b);
        s16x8 af[4], bf_[4];
#pragma unroll
        for (int i = 0; i < 4; ++i) {
            af[i]  = *(const s16x8*)&Alds[cur][kcl][arow0 + i * 16][0];
            bf_[i] = *(const s16x8*)&Blds[cur][kcl][brow0 + i * 16][0];
        }
#pragma unroll
        for (int i = 0; i < 4; ++i)
#pragma unroll
            for (int j = 0; j < 4; ++j)
                acc[i][j] = __builtin_amdgcn_mfma_f32_16x16x32_bf16(
                    af[i], bf_[j], acc[i][j], 0, 0, 0);
        if (t + 1 < NT) stage_write(cur ^ 1, a, b, coef(t + 1));
        __syncthreads();
        cur ^= 1;
    }
    const int gm0 = m_tile * 128 + (wv >> 1) * 64 + kcl * 4;
    const int gn0 = n_tile * 128 + (wv & 1) * 64 + frow;
#pragma unroll
    for (int j = 0; j < 4; ++j) {
        const int n = gn0 + j * 16;
        const float bc = bias[n] * row_bias_coef(n, w);
#pragma unroll
        for (int i = 0; i < 4; ++i) {
            float* yp = Y + (size_t)(gm0 + i * 16) * NDIM + n;
            yp[0 * NDIM] = acc[i][j][0] + bc;
            yp[1 * NDIM] = acc[i][j][1] + bc;
            yp[2 * NDIM] = acc[i][j][2] + bc;
            yp[3 * NDIM] = acc[i][j][3] + bc;
        }
    }
}

extern "C" void kernel_launch(void* const* d_in, const int* in_sizes, int n_in,
                              void* d_out, int out_size, void* d_ws, size_t ws_size,
                              hipStream_t stream) {
    const float* X    = (const float*)d_in[0];
    const float* wts  = (const float*)d_in[1];
    const float* W    = (const float*)d_in[2];
    const float* bias = (const float*)d_in[3];
    float* Y = (float*)d_out;

    const int M = in_sizes[0] / KDIM;            // 32768

    const size_t xb_elems = (size_t)M * KDIM;
    const size_t wb_elems = (size_t)NDIM * KDIM;
    const size_t ws_needed = (xb_elems + wb_elems) * sizeof(unsigned short);

    if (ws_size >= ws_needed && (M % 128) == 0) {
        unsigned short* XB = (unsigned short*)d_ws;
        unsigned short* WB = XB + xb_elems;
        const int xchunks   = (int)(xb_elems / 8);           // 4,194,304
        const int totchunks = xchunks + (int)(wb_elems / 8); // + 524,288
        prep_all<<<(totchunks + 255) / 256, 256, 0, stream>>>(X, W, wts, XB, WB,
                                                              xchunks, totchunks);
        const int grid = (M / 128) * (NDIM / 256);   // 4096
        mlv2_gemm_v13<<<grid, 512, 0, stream>>>(XB, WB, wts, bias, Y);
    } else {
        const int grid = (M / 128) * (NDIM / 128);
        mlv2_gemm_v1<<<grid, 256, 0, stream>>>(X, wts, W, bias, Y);
    }
}